// Round 13
// baseline (1303.046 us; speedup 1.0000x reference)
//
#include <hip/hip_runtime.h>
#include <hip/hip_bf16.h>

// GptOss grouped experts, round 13: concurrency at constant volume.
// R10 (1 blk/CU, 10 B/cyc delivery) vs R12 (2 blk/CU, 18 B/cyc but 2x volume)
// triangulate: big tile + 2 blocks/CU. gemm1: 256x256, BK=32 -> LDS dbuf
// 64 KB -> 2 blocks/CU; same 2-barrier counted-vmcnt loop (halves = fn-split);
// 4 glds/wave/tile uniform -> vmcnt(4); swizzle re-derived for 64B rows
// (chunk ^= (row>>1)&3, 2-way = free). N=5760 -> 23 padded n-tiles (clamped
// staging + predicated epilogue). gemm2 + fused cvt byte-identical to R10/R12.

#define TT   16384
#define DIM_ 2880
#define HID_ 2880
#define NE   8
#define TPE  2048
#define KDIM 2880
#define NTK  90     // KDIM / 32 (gemm1)
#define NT   45     // KDIM / 64 (gemm2)
#define NB1  5760
#define NT1P 23     // padded n-tiles of 256
#define NX   ((long)TT * DIM_)
#define N1   ((long)NE * 2 * HID_ * DIM_)
#define N2   ((long)NE * DIM_ * HID_)

typedef __attribute__((ext_vector_type(8))) short short8;
typedef __attribute__((ext_vector_type(4))) float f32x4;

__device__ __forceinline__ unsigned short f2bf(float f) {
  unsigned u = __builtin_bit_cast(unsigned, f);
  u += 0x7fffu + ((u >> 16) & 1u);   // round-to-nearest-even
  return (unsigned short)(u >> 16);
}

__device__ __forceinline__ void cvt8(const float* __restrict__ s,
                                     unsigned short* __restrict__ d) {
  float4 a = *(const float4*)s;
  float4 b = *(const float4*)(s + 4);
  union { unsigned short u[8]; short8 v; } r;
  r.u[0] = f2bf(a.x); r.u[1] = f2bf(a.y); r.u[2] = f2bf(a.z); r.u[3] = f2bf(a.w);
  r.u[4] = f2bf(b.x); r.u[5] = f2bf(b.y); r.u[6] = f2bf(b.z); r.u[7] = f2bf(b.w);
  *(short8*)d = r.v;
}

__global__ void __launch_bounds__(256) cvt_all(const float* __restrict__ x,
                                               const float* __restrict__ w1,
                                               const float* __restrict__ w2,
                                               unsigned short* __restrict__ xb,
                                               unsigned short* __restrict__ w1b,
                                               unsigned short* __restrict__ w2b) {
  long i = ((long)blockIdx.x * 256 + threadIdx.x) * 8;
  if (i < NX)           cvt8(x  + i,        xb  + i);
  else if (i < NX + N1) cvt8(w1 + (i - NX), w1b + (i - NX));
  else                  cvt8(w2 + (i - NX - N1), w2b + (i - NX - N1));
}

#define GLDS(gsrc, ldst) \
  __builtin_amdgcn_global_load_lds( \
      (const __attribute__((address_space(1))) unsigned int*)(gsrc), \
      (__attribute__((address_space(3))) unsigned int*)(ldst), 16, 0, 0)

#define MFMA_(a, b, c) __builtin_amdgcn_mfma_f32_16x16x32_bf16(a, b, c, 0, 0, 0)

// ---------------- GEMM1: 256x256, BK=32, 8 waves, 2 blocks/CU --------------
// A=xb [E][2048][2880], B=w1b [E][5760][2880]. Grid (184,1,E):
// XCD c owns m-tile c (A panel 1.5MB L2-resident); l = n-tile 0..22.
__global__ void __launch_bounds__(512, 2) gemm1_k32(const unsigned short* __restrict__ A,
                                                    const unsigned short* __restrict__ B,
                                                    const float* __restrict__ bias,
                                                    unsigned short* __restrict__ ha) {
  __shared__ unsigned short As[2][256 * 32];   // 16 KB per buf
  __shared__ unsigned short Bs[2][256 * 32];

  const int tid  = threadIdx.x;
  const int lane = tid & 63;
  const int wid  = tid >> 6;        // 0..7
  const int wr   = wid >> 2;        // 0..1
  const int wc   = wid & 3;         // 0..3
  const int e    = blockIdx.z;
  const int bid  = blockIdx.x;

  const int m0 = (bid & 7) * 256;   // XCD-owned m-tile
  const int n0 = (bid >> 3) * 256;  // 0..22 (tile 22 partial: cols 5632..5759)

  // staging: wave w covers rows [32w,32w+32) as 2 units of 16 rows (1KB/unit).
  // lane -> row_in_unit = lane>>2, chunk = lane&3 (16B chunks of 64B row).
  // T2 inverse-swizzle: src chunk = (lane&3) ^ ((row>>1)&3) = (lane&3)^((lane>>3)&3).
  const int srow = (wid << 5) + (lane >> 2);                 // unit-0 row, 0..255
  const int sc   = (((lane & 3) ^ ((lane >> 3) & 3)) << 3);  // element offset
  const unsigned short* Ae = A + ((size_t)e * TPE + m0 + srow) * KDIM + sc;
  const unsigned short* Be = B + (size_t)e * NB1 * KDIM + sc;
  const int brow0 = n0 + srow;                               // may exceed 5759

  auto stage = [&](int buf, int kt) {
#pragma unroll
    for (int u = 0; u < 2; ++u) {
      GLDS(Ae + (size_t)(u * 16) * KDIM + kt * 32,
           &As[buf][(wid * 2 + u) * 512 + lane * 8]);
      int gr = brow0 + u * 16;
      gr = gr < NB1 ? gr : NB1 - 1;              // clamp pad rows (finite junk)
      GLDS(Be + (size_t)gr * KDIM + kt * 32,
           &Bs[buf][(wid * 2 + u) * 512 + lane * 8]);
    }
  };

  // fragment reads (swizzled): row = base + fm*16 + (lane&15), kchunk = lane>>4
  // byte = row*64 + ((lane>>4) ^ ((row>>1)&3))*16; row-XOR bits = (lane>>1)&3.
  const int kx   = (((lane >> 4) ^ ((lane >> 1) & 3)) << 4);
  const int arow = (wr * 128 + (lane & 15)) * 64 + kx;
  const int brow = (wc * 64  + (lane & 15)) * 64 + kx;

  f32x4 acc[8][4] = {};

  stage(0, 0);
  stage(1, 1);
  asm volatile("s_waitcnt vmcnt(4)" ::: "memory");
  __builtin_amdgcn_s_barrier();

  for (int t = 0; t < NTK; ++t) {
    const int cur = t & 1;
    const char* aB = (const char*)(&As[cur][0]) + arow;
    const char* bB = (const char*)(&Bs[cur][0]) + brow;

    short8 a[8], b[4];
#pragma unroll
    for (int fm = 0; fm < 8; ++fm) a[fm] = *(const short8*)(aB + fm * 1024);
#pragma unroll
    for (int fn = 0; fn < 4; ++fn) b[fn] = *(const short8*)(bB + fn * 1024);

    // half 1: fn 0-1 (16 MFMA), overlaps remaining ds_reads via counted lgkm
#pragma unroll
    for (int fn = 0; fn < 2; ++fn)
#pragma unroll
      for (int fm = 0; fm < 8; ++fm)
        acc[fm][fn] = MFMA_(a[fm], b[fn], acc[fm][fn]);

    asm volatile("s_waitcnt lgkmcnt(0)" ::: "memory");
    __builtin_amdgcn_s_barrier();

    const bool more = (t + 2 < NTK);
    if (more) stage(cur, t + 2);     // overwrite vacated buffer

    __builtin_amdgcn_s_setprio(1);
#pragma unroll
    for (int fn = 2; fn < 4; ++fn)
#pragma unroll
      for (int fm = 0; fm < 8; ++fm)
        acc[fm][fn] = MFMA_(a[fm], b[fn], acc[fm][fn]);
    __builtin_amdgcn_s_setprio(0);

    if (more) asm volatile("s_waitcnt vmcnt(4)" ::: "memory");
    else      asm volatile("s_waitcnt vmcnt(0)" ::: "memory");
    __builtin_amdgcn_s_barrier();
  }

  // epilogue: bias + SwiGLU -> ha bf16 [E][2048][2880]; predicated col<5760
  const float* be = bias + (size_t)e * NB1;
  unsigned short* hae = ha + (size_t)e * TPE * HID_;
#pragma unroll
  for (int fm = 0; fm < 8; ++fm)
#pragma unroll
    for (int fn = 0; fn < 4; ++fn) {
      const int col = n0 + wc * 64 + fn * 16 + (lane & 15);
      const bool ok = col < NB1;
      const float bc = ok ? be[col] : 0.0f;
#pragma unroll
      for (int j = 0; j < 4; ++j) {
        const int row = m0 + wr * 128 + fm * 16 + (lane >> 4) * 4 + j;
        float v = acc[fm][fn][j] + bc;
        float p = __shfl_xor(v, 1);   // partner column
        if (!(lane & 1) && ok) {
          float g  = fminf(v, 7.0f);
          float l2 = fminf(fmaxf(p, -7.0f), 7.0f);
          float act = g / (1.0f + __expf(-1.702f * g)) * (l2 + 1.0f);
          hae[(size_t)row * HID_ + (col >> 1)] = f2bf(act);
        }
      }
    }
}

// ---------------- GEMM2: R7/R10 verified kernel (256x320, FN=5) ------------
__global__ void __launch_bounds__(512, 2) gemm2k(const unsigned short* __restrict__ A,
                                                 const unsigned short* __restrict__ B,
                                                 const float* __restrict__ bias,
                                                 float* __restrict__ Cout,
                                                 int M, int N) {
  __shared__ unsigned short As[2][256 * 64];
  __shared__ unsigned short Bs[2][320 * 64];

  const int tid  = threadIdx.x;
  const int lane = tid & 63;
  const int wid  = tid >> 6;
  const int wr   = wid >> 2;
  const int wc   = wid & 3;
  const int e    = blockIdx.z;

  const int ntn   = N / 320;
  const int per_e = ntn * (M / 256);
  const int bid   = blockIdx.x;
  const int swz   = (bid & 7) * (per_e >> 3) + (bid >> 3);
  const int m0    = (swz / ntn) * 256;
  const int n0    = (swz % ntn) * 320;

  const int srow = tid >> 3;
  const int scol = ((tid & 7) ^ (srow & 7)) << 3;
  const unsigned short* Aexp = A + ((size_t)e * M + m0 + srow) * KDIM + scol;
  const unsigned short* Bexp = B + ((size_t)e * N + n0 + srow) * KDIM + scol;

  auto stage = [&](int buf, int kt) {
    const unsigned short* asrc = Aexp + (size_t)kt * 64;
#pragma unroll
    for (int j = 0; j < 4; ++j)
      GLDS(asrc + (size_t)(j * 64) * KDIM, &As[buf][j * 4096 + tid * 8]);
    const unsigned short* bsrc = Bexp + (size_t)kt * 64;
#pragma unroll
    for (int j = 0; j < 5; ++j)
      GLDS(bsrc + (size_t)(j * 64) * KDIM, &Bs[buf][j * 4096 + tid * 8]);
  };

  const int arow = (wr * 128 + (lane & 15)) * 128;
  const int brow = (wc * 80  + (lane & 15)) * 128;
  const int swzb = (lane & 7) << 4;
  const int kb   = ((lane >> 4) & 3) * 16;
  const int c0 = kb ^ swzb;
  const int c1 = (64 + kb) ^ swzb;

  f32x4 acc[8][5] = {};

  stage(0, 0);
  stage(1, 1);
  asm volatile("s_waitcnt vmcnt(9)" ::: "memory");
  __builtin_amdgcn_s_barrier();

  for (int t = 0; t < NT; ++t) {
    const int cur = t & 1;
    const char* aB = (const char*)(&As[cur][0]) + arow;
    const char* bB = (const char*)(&Bs[cur][0]) + brow;

    short8 a0[8], a1[8], b0[5], b1[5];
#pragma unroll
    for (int fm = 0; fm < 8; ++fm) {
      a0[fm] = *(const short8*)(aB + fm * 2048 + c0);
      a1[fm] = *(const short8*)(aB + fm * 2048 + c1);
    }
#pragma unroll
    for (int fn = 0; fn < 5; ++fn) {
      b0[fn] = *(const short8*)(bB + fn * 2048 + c0);
      b1[fn] = *(const short8*)(bB + fn * 2048 + c1);
    }

#pragma unroll
    for (int fn = 0; fn < 5; ++fn)
#pragma unroll
      for (int fm = 0; fm < 8; ++fm)
        acc[fm][fn] = MFMA_(a0[fm], b0[fn], acc[fm][fn]);

    asm volatile("s_waitcnt lgkmcnt(0)" ::: "memory");
    __builtin_amdgcn_s_barrier();

    const bool more = (t + 2 < NT);
    if (more) stage(cur, t + 2);

    __builtin_amdgcn_s_setprio(1);
#pragma unroll
    for (int fn = 0; fn < 5; ++fn)
#pragma unroll
      for (int fm = 0; fm < 8; ++fm)
        acc[fm][fn] = MFMA_(a1[fm], b1[fn], acc[fm][fn]);
    __builtin_amdgcn_s_setprio(0);

    if (more) asm volatile("s_waitcnt vmcnt(9)" ::: "memory");
    else      asm volatile("s_waitcnt vmcnt(0)" ::: "memory");
    __builtin_amdgcn_s_barrier();
  }

  const float* be = bias + (size_t)e * N;
  float* out = Cout + (size_t)e * (size_t)M * N;
#pragma unroll
  for (int fm = 0; fm < 8; ++fm)
#pragma unroll
    for (int fn = 0; fn < 5; ++fn) {
      const int col = n0 + wc * 80 + fn * 16 + (lane & 15);
      const float bc = be[col];
#pragma unroll
      for (int j = 0; j < 4; ++j) {
        const int row = m0 + wr * 128 + fm * 16 + (lane >> 4) * 4 + j;
        out[(size_t)row * N + col] = acc[fm][fn][j] + bc;
      }
    }
}

extern "C" void kernel_launch(void* const* d_in, const int* in_sizes, int n_in,
                              void* d_out, int out_size, void* d_ws, size_t ws_size,
                              hipStream_t stream) {
  const float* x  = (const float*)d_in[0];
  // d_in[1] = num_tokens_per_expert: fixed T/E split (reference ignores it)
  const float* w1 = (const float*)d_in[2];
  const float* b1 = (const float*)d_in[3];
  const float* w2 = (const float*)d_in[4];
  const float* b2 = (const float*)d_in[5];

  unsigned short* xb  = (unsigned short*)d_ws;
  unsigned short* w1b = xb  + NX;
  unsigned short* w2b = w1b + N1;
  unsigned short* ha  = w2b + N2;

  // fused fp32->bf16 conversion (x | w1 | w2)
  const long ntot = NX + N1 + N2;
  cvt_all<<<(int)(ntot / 2048), 256, 0, stream>>>(x, w1, w2, xb, w1b, w2b);

  // GEMM1 + bias + swiglu -> ha; 256x256 BK=32, 2 blocks/CU, 23 padded n-tiles
  dim3 g1(8 * NT1P, 1, NE);                    // 184 per expert
  gemm1_k32<<<g1, 512, 0, stream>>>(xb, w1b, b1, ha);

  // GEMM2 + bias -> out (fp32 [T][2880]); unchanged
  dim3 g2((DIM_ / 320) * (TPE / 256), 1, NE);  // 72 per expert
  gemm2k<<<g2, 512, 0, stream>>>(ha, w2b, b2, (float*)d_out, TPE, DIM_);
}

// Round 14
// 1157.670 us; speedup vs baseline: 1.1256x; 1.1256x over previous
//
#include <hip/hip_runtime.h>
#include <hip/hip_bf16.h>

// GptOss grouped experts, round 14 (final config): restore verified-best R10.
// gemm1: 256x320 (FN=5), 2-barrier counted-vmcnt loop, T2 XOR swizzle via
// inverse-swizzled source, T5 setprio, 2D XCD chunking (2m x 9n pair-
// interleaved -> FETCH 1.1GB -> 657MB). gemm2: same template, 1D swizzle.
// Single fused cvt launch (x|w1|w2) -- verified equal/better than 3 launches.
// 13-round ledger: all structural deviations regressed (fine-phase x3,
// 1-barrier, FN=6, 128^2 multi-block, BK=32 multi-block). This config =
// gemm1 879 TF / gemm2 915 TF = the plain-HIP 2-barrier ceiling (~900 TF).

#define TT   16384
#define DIM_ 2880
#define HID_ 2880
#define NE   8
#define TPE  2048
#define KDIM 2880
#define NT   45     // KDIM / 64
#define NX   ((long)TT * DIM_)            // 47,185,920
#define N1   ((long)NE * 2 * HID_ * DIM_) // 132,710,400
#define N2   ((long)NE * DIM_ * HID_)     // 66,355,200

typedef __attribute__((ext_vector_type(8))) short short8;
typedef __attribute__((ext_vector_type(4))) float f32x4;

__device__ __forceinline__ unsigned short f2bf(float f) {
  unsigned u = __builtin_bit_cast(unsigned, f);
  u += 0x7fffu + ((u >> 16) & 1u);   // round-to-nearest-even
  return (unsigned short)(u >> 16);
}

__device__ __forceinline__ void cvt8(const float* __restrict__ s,
                                     unsigned short* __restrict__ d) {
  float4 a = *(const float4*)s;
  float4 b = *(const float4*)(s + 4);
  union { unsigned short u[8]; short8 v; } r;
  r.u[0] = f2bf(a.x); r.u[1] = f2bf(a.y); r.u[2] = f2bf(a.z); r.u[3] = f2bf(a.w);
  r.u[4] = f2bf(b.x); r.u[5] = f2bf(b.y); r.u[6] = f2bf(b.z); r.u[7] = f2bf(b.w);
  *(short8*)d = r.v;
}

__global__ void __launch_bounds__(256) cvt_all(const float* __restrict__ x,
                                               const float* __restrict__ w1,
                                               const float* __restrict__ w2,
                                               unsigned short* __restrict__ xb,
                                               unsigned short* __restrict__ w1b,
                                               unsigned short* __restrict__ w2b) {
  long i = ((long)blockIdx.x * 256 + threadIdx.x) * 8;
  if (i < NX)           cvt8(x  + i,        xb  + i);
  else if (i < NX + N1) cvt8(w1 + (i - NX), w1b + (i - NX));
  else                  cvt8(w2 + (i - NX - N1), w2b + (i - NX - N1));
}

#define GLDS(gsrc, ldst) \
  __builtin_amdgcn_global_load_lds( \
      (const __attribute__((address_space(1))) unsigned int*)(gsrc), \
      (__attribute__((address_space(3))) unsigned int*)(ldst), 16, 0, 0)

// C = A(MxK) * B(NxK)^T, bf16 in, fp32 accum. BM=256, BN=320, BK=64.
// 512 threads = 8 waves (2M x 4N); per-wave 128x80 (FM=8, FN=5).
// CH2D: gemm1's 2m x 9n pair-interleaved XCD chunking (ntm=8, ntn=18).
// LDS: dbuf x (A 32KB + B 40KB) = 144 KB -> 1 block/CU.
template<bool FUSE_SWIGLU, bool CH2D>
__global__ void __launch_bounds__(512, 2) gemm8(const unsigned short* __restrict__ A,
                                                const unsigned short* __restrict__ B,
                                                const float* __restrict__ bias,
                                                void* __restrict__ Cout,
                                                int M, int N) {
  __shared__ unsigned short As[2][256 * 64];
  __shared__ unsigned short Bs[2][320 * 64];

  const int tid  = threadIdx.x;
  const int lane = tid & 63;
  const int wid  = tid >> 6;
  const int wr   = wid >> 2;        // 0..1
  const int wc   = wid & 3;         // 0..3
  const int e    = blockIdx.z;
  const int bid  = blockIdx.x;

  int m0, n0;
  if constexpr (CH2D) {
    // 8x18 tile grid, 4x2 chunks of 2m x 9n; pair-interleaved traversal.
    const int c  = bid & 7;         // chunk id (XCD)
    const int l  = bid >> 3;        // 0..17, dispatch-consecutive on this XCD
    const int cm = c >> 1;          // 0..3
    const int cn = c & 1;           // 0..1
    m0 = (cm * 2 + (l & 1)) * 256;  // alternate m fastest
    n0 = (cn * 9 + (l >> 1)) * 320; // same n for consecutive block pairs
  } else {
    const int ntn   = N / 320;
    const int per_e = ntn * (M / 256);
    const int swz   = (bid & 7) * (per_e >> 3) + (bid >> 3);
    m0 = (swz / ntn) * 256;
    n0 = (swz % ntn) * 320;
  }

  // staging: 8 lanes/row, 16B/lane; T2 inverse-swizzle on source column
  const int srow = tid >> 3;                         // 0..63
  const int scol = ((tid & 7) ^ (srow & 7)) << 3;    // elements
  const unsigned short* Aexp = A + ((size_t)e * M + m0 + srow) * KDIM + scol;
  const unsigned short* Bexp = B + ((size_t)e * N + n0 + srow) * KDIM + scol;

  auto stage = [&](int buf, int kt) {
    const unsigned short* asrc = Aexp + (size_t)kt * 64;
#pragma unroll
    for (int j = 0; j < 4; ++j)
      GLDS(asrc + (size_t)(j * 64) * KDIM, &As[buf][j * 4096 + tid * 8]);
    const unsigned short* bsrc = Bexp + (size_t)kt * 64;
#pragma unroll
    for (int j = 0; j < 5; ++j)
      GLDS(bsrc + (size_t)(j * 64) * KDIM, &Bs[buf][j * 4096 + tid * 8]);
  };

  // fragment-read addressing (swizzled), byte offsets; row stride 128 B
  const int arow = (wr * 128 + (lane & 15)) * 128;
  const int brow = (wc * 80  + (lane & 15)) * 128;
  const int swzb = (lane & 7) << 4;
  const int kb   = ((lane >> 4) & 3) * 16;
  const int c0 = kb ^ swzb;          // kk=0
  const int c1 = (64 + kb) ^ swzb;   // kk=1

  f32x4 acc[8][5] = {};

  // prologue: tiles 0,1 staged (9 loads each); wait tile 0.
  stage(0, 0);
  stage(1, 1);
  asm volatile("s_waitcnt vmcnt(9)" ::: "memory");
  __builtin_amdgcn_s_barrier();

  for (int t = 0; t < NT; ++t) {
    const int cur = t & 1;
    const char* aB = (const char*)(&As[cur][0]) + arow;
    const char* bB = (const char*)(&Bs[cur][0]) + brow;

    short8 a0[8], a1[8], b0[5], b1[5];
#pragma unroll
    for (int fm = 0; fm < 8; ++fm) {
      a0[fm] = *(const short8*)(aB + fm * 2048 + c0);
      a1[fm] = *(const short8*)(aB + fm * 2048 + c1);
    }
#pragma unroll
    for (int fn = 0; fn < 5; ++fn) {
      b0[fn] = *(const short8*)(bB + fn * 2048 + c0);
      b1[fn] = *(const short8*)(bB + fn * 2048 + c1);
    }

    // kk=0 MFMAs overlap kk=1 ds_reads (compiler counted lgkmcnt)
#pragma unroll
    for (int fn = 0; fn < 5; ++fn)
#pragma unroll
      for (int fm = 0; fm < 8; ++fm)
        acc[fm][fn] = __builtin_amdgcn_mfma_f32_16x16x32_bf16(a0[fm], b0[fn], acc[fm][fn], 0, 0, 0);

    // all our ds_reads done -> buffer free; barrier makes it true for all waves
    asm volatile("s_waitcnt lgkmcnt(0)" ::: "memory");
    __builtin_amdgcn_s_barrier();

    const bool more = (t + 2 < NT);
    if (more) stage(cur, t + 2);     // overwrite vacated buffer

    __builtin_amdgcn_s_setprio(1);
#pragma unroll
    for (int fn = 0; fn < 5; ++fn)
#pragma unroll
      for (int fm = 0; fm < 8; ++fm)
        acc[fm][fn] = __builtin_amdgcn_mfma_f32_16x16x32_bf16(a1[fm], b1[fn], acc[fm][fn], 0, 0, 0);
    __builtin_amdgcn_s_setprio(0);

    // counted vmcnt: wait tile t+1 complete, leave tile t+2's 9 loads in flight
    if (more) asm volatile("s_waitcnt vmcnt(9)" ::: "memory");
    else      asm volatile("s_waitcnt vmcnt(0)" ::: "memory");
    __builtin_amdgcn_s_barrier();
  }

  // ---- epilogue
  const float* be = bias + (size_t)e * N;
  if constexpr (FUSE_SWIGLU) {
    unsigned short* ha = (unsigned short*)Cout + (size_t)e * M * (N >> 1);
#pragma unroll
    for (int fm = 0; fm < 8; ++fm)
#pragma unroll
      for (int fn = 0; fn < 5; ++fn) {
        const int col = n0 + wc * 80 + fn * 16 + (lane & 15);
        const float bc = be[col];
#pragma unroll
        for (int j = 0; j < 4; ++j) {
          const int row = m0 + wr * 128 + fm * 16 + (lane >> 4) * 4 + j;
          float v = acc[fm][fn][j] + bc;
          float p = __shfl_xor(v, 1);   // partner column (all lanes execute)
          if (!(lane & 1)) {
            float g  = fminf(v, 7.0f);
            float l2 = fminf(fmaxf(p, -7.0f), 7.0f);
            float act = g / (1.0f + __expf(-1.702f * g)) * (l2 + 1.0f);
            ha[(size_t)row * (N >> 1) + (col >> 1)] = f2bf(act);
          }
        }
      }
  } else {
    float* out = (float*)Cout + (size_t)e * M * N;
#pragma unroll
    for (int fm = 0; fm < 8; ++fm)
#pragma unroll
      for (int fn = 0; fn < 5; ++fn) {
        const int col = n0 + wc * 80 + fn * 16 + (lane & 15);
        const float bc = be[col];
#pragma unroll
        for (int j = 0; j < 4; ++j) {
          const int row = m0 + wr * 128 + fm * 16 + (lane >> 4) * 4 + j;
          out[(size_t)row * N + col] = acc[fm][fn][j] + bc;
        }
      }
  }
}

extern "C" void kernel_launch(void* const* d_in, const int* in_sizes, int n_in,
                              void* d_out, int out_size, void* d_ws, size_t ws_size,
                              hipStream_t stream) {
  const float* x  = (const float*)d_in[0];
  // d_in[1] = num_tokens_per_expert: fixed T/E split (reference ignores it)
  const float* w1 = (const float*)d_in[2];
  const float* b1 = (const float*)d_in[3];
  const float* w2 = (const float*)d_in[4];
  const float* b2 = (const float*)d_in[5];

  unsigned short* xb  = (unsigned short*)d_ws;
  unsigned short* w1b = xb  + NX;
  unsigned short* w2b = w1b + N1;
  unsigned short* ha  = w2b + N2;

  // fused fp32->bf16 conversion (x | w1 | w2)
  const long ntot = NX + N1 + N2;              // 246,251,520 (div by 2048)
  cvt_all<<<(int)(ntot / 2048), 256, 0, stream>>>(x, w1, w2, xb, w1b, w2b);

  // GEMM1 + bias + swiglu -> ha (bf16 [E][2048][2880]); 2D XCD chunking
  dim3 g1((5760 / 320) * (TPE / 256), 1, NE);   // 18*8 = 144 per expert
  gemm8<true, true><<<g1, 512, 0, stream>>>(xb, w1b, b1, ha, TPE, 5760);

  // GEMM2 + bias -> out (fp32 [T][2880]); 1D swizzle (9x8 grid)
  dim3 g2((DIM_ / 320) * (TPE / 256), 1, NE);   // 9*8 = 72 per expert
  gemm8<false, false><<<g2, 512, 0, stream>>>(ha, w2b, b2, (float*)d_out, TPE, DIM_);
}